// Round 9
// baseline (421.476 us; speedup 1.0000x reference)
//
#include <hip/hip_runtime.h>

#define HH 256
#define WW 128
#define DD 256
#define HID 8
#define G 16              // samples per block
#define PSTRIDE 272       // padded per-patch stride in floats (256 + 16): mod 32 == 16
#define IMG (HH * WW)     // 32768 floats per sample

typedef float v4f __attribute__((ext_vector_type(4)));

__device__ __forceinline__ float rlane(float v, int l) {
    return __int_as_float(__builtin_amdgcn_readlane(__float_as_int(v), l));
}

__global__ __launch_bounds__(512, 6)   // 6 waves/EU -> 3 blocks/CU; VGPR cap 80
void lca_kernel(const float* __restrict__ x, const float* __restrict__ We,
                const float* __restrict__ be, const float* __restrict__ Wd,
                const float* __restrict__ bd, float* __restrict__ out) {
    __shared__ float Xb[2][8 * PSTRIDE];   // staged input, patch-major, dbuf
    __shared__ float Ob[2][8 * PSTRIDE];   // staged output, patch-major, dbuf

    const int bid = blockIdx.x;
    const int ph  = bid & 15;              // stripe (16 rows of the image)
    const int sg  = bid >> 4;              // sample group 0..127
    const int tid = threadIdx.x;
    const int w   = tid >> 6;              // wave index == patch pw within stripe
    const int l   = tid & 63;
    const int p   = ph * 8 + w;            // global patch id for this wave

    // stage mapping: thread t handles the contiguous float4 at stripe offset 4t
    const int r_t  = tid >> 5;
    const int pw_t = (tid >> 2) & 7;
    const int jj_t = (tid & 3) * 4;
    const int lds_stage = pw_t * PSTRIDE + r_t * 16 + jj_t;   // patch-major slot
    const int goff = tid * 4;                                  // contiguous offset

    // ---- weight preload (per wave, its patch) ----
    v4f we4[HID];
#pragma unroll
    for (int h = 0; h < HID; ++h)
        we4[h] = *(const v4f*)(We + ((size_t)(p * HID + h)) * DD + l * 4);
    float bev[HID];
#pragma unroll
    for (int h = 0; h < HID; ++h) bev[h] = be[p * HID + h];
    v4f wd4[4][2];
#pragma unroll
    for (int c = 0; c < 4; ++c) {
        const v4f* wp = (const v4f*)(Wd + ((size_t)(p * DD + l * 4 + c)) * HID);
        wd4[c][0] = wp[0];
        wd4[c][1] = wp[1];
    }
    v4f bdv = *(const v4f*)(bd + p * DD + l * 4);

    const bool b5 = (l & 32) != 0;
    const bool b4 = (l & 16) != 0;
    const bool b3 = (l & 8)  != 0;

    // stripe is CONTIGUOUS in memory: rows ph*16 .. ph*16+15
    const float* xs = x   + (size_t)(sg * G) * IMG + ph * 2048;
    float*       os = out + (size_t)(sg * G) * IMG + ph * 2048;

    // prologue: stage sample 0; hold sample 1 in regs
    {
        v4f x0 = *(const v4f*)(xs + goff);
        *(v4f*)&Xb[0][lds_stage] = x0;
    }
    v4f xn = *(const v4f*)(xs + IMG + goff);

#pragma unroll 1
    for (int s = 0; s < G; ++s) {
        __syncthreads();   // the ONLY barrier per sample

        // issue load for sample s+2 AFTER the barrier: it drains at the NEXT
        // barrier, with this whole compute+stage+store phase hiding its latency
        v4f xm;
        if (s + 2 < G)
            xm = *(const v4f*)(xs + (size_t)(s + 2) * IMG + goff);

        // ---- compute sample s: wave w owns patch p; lane l owns d = 4l..4l+3
        v4f xv = *(const v4f*)&Xb[s & 1][w * PSTRIDE + 4 * l];

        float z[HID];
#pragma unroll
        for (int h = 0; h < HID; ++h)
            z[h] = fmaf(we4[h].x, xv.x,
                   fmaf(we4[h].y, xv.y,
                   fmaf(we4[h].z, xv.z, we4[h].w * xv.w)));

        // reduce-scatter: mask32 keep 4, mask16 keep 2, mask8 keep 1
        float a[4];
#pragma unroll
        for (int c = 0; c < 4; ++c) {
            float send = b5 ? z[c]     : z[c + 4];
            float keep = b5 ? z[c + 4] : z[c];
            a[c] = keep + __shfl_xor(send, 32);
        }
        float bb[2];
#pragma unroll
        for (int c = 0; c < 2; ++c) {
            float send = b4 ? a[c]     : a[c + 2];
            float keep = b4 ? a[c + 2] : a[c];
            bb[c] = keep + __shfl_xor(send, 16);
        }
        float s1;
        {
            float send = b3 ? bb[0] : bb[1];
            float keep = b3 ? bb[1] : bb[0];
            s1 = keep + __shfl_xor(send, 8);
        }
#pragma unroll
        for (int m = 4; m >= 1; m >>= 1)
            s1 += __shfl_xor(s1, m);

        // broadcast (h lives at lane h*8) + decode + sigmoid
        float zf[HID];
#pragma unroll
        for (int h = 0; h < HID; ++h)
            zf[h] = rlane(s1, h * 8) + bev[h];

        v4f o;
#pragma unroll
        for (int c = 0; c < 4; ++c) {
            float acc = bdv[c];
#pragma unroll
            for (int h = 0; h < 4; ++h) acc = fmaf(wd4[c][0][h], zf[h], acc);
#pragma unroll
            for (int h = 0; h < 4; ++h) acc = fmaf(wd4[c][1][h], zf[h + 4], acc);
            o[c] = __builtin_amdgcn_rcpf(1.0f + __expf(-acc));
        }
        *(v4f*)&Ob[s & 1][w * PSTRIDE + 4 * l] = o;

        // stage next sample's input (reg-held since previous iteration)
        if (s + 1 < G)
            *(v4f*)&Xb[(s + 1) & 1][lds_stage] = xn;

        // store PREVIOUS sample's output (written before this iter's barrier)
        if (s > 0) {
            v4f ov = *(const v4f*)&Ob[(s - 1) & 1][lds_stage];
            __builtin_nontemporal_store(ov, (v4f*)(os + (size_t)(s - 1) * IMG + goff));
        }
        xn = xm;
    }

    // epilogue: store the last sample
    __syncthreads();
    {
        v4f ov = *(const v4f*)&Ob[(G - 1) & 1][lds_stage];
        __builtin_nontemporal_store(ov, (v4f*)(os + (size_t)(G - 1) * IMG + goff));
    }
}

extern "C" void kernel_launch(void* const* d_in, const int* in_sizes, int n_in,
                              void* d_out, int out_size, void* d_ws, size_t ws_size,
                              hipStream_t stream) {
    const float* x  = (const float*)d_in[0];
    const float* We = (const float*)d_in[1];
    const float* be = (const float*)d_in[2];
    const float* Wd = (const float*)d_in[3];
    const float* bd = (const float*)d_in[4];
    float* out = (float*)d_out;

    const int n_total = in_sizes[0] / IMG;          // 2048
    const int grid    = 16 * (n_total / G);         // 16 stripes * 128 groups = 2048
    lca_kernel<<<dim3(grid), dim3(512), 0, stream>>>(x, We, be, Wd, bd, out);
}

// Round 10
// 114.064 us; speedup vs baseline: 3.6951x; 3.6951x over previous
//
#include <hip/hip_runtime.h>

#define HH 256
#define WW 128
#define DD 256
#define HID 8
#define G 16              // samples per block
#define PSTRIDE 272       // padded per-patch stride in floats (256 + 16): mod 32 == 16
#define IMG (HH * WW)     // 32768 floats per sample

typedef float v4f __attribute__((ext_vector_type(4)));

__device__ __forceinline__ float rlane(float v, int l) {
    return __int_as_float(__builtin_amdgcn_readlane(__float_as_int(v), l));
}

__global__ __launch_bounds__(512, 4)   // (512,6) spilled to scratch: 421us. Keep 4.
void lca_kernel(const float* __restrict__ x, const float* __restrict__ We,
                const float* __restrict__ be, const float* __restrict__ Wd,
                const float* __restrict__ bd, float* __restrict__ out) {
    __shared__ float Xb[2][8 * PSTRIDE];   // staged input, patch-major, dbuf
    __shared__ float Ob[2][8 * PSTRIDE];   // staged output, patch-major, dbuf

    const int bid = blockIdx.x;
    const int ph  = bid & 15;              // stripe (16 rows of the image)
    const int sg  = bid >> 4;              // sample group 0..127
    const int tid = threadIdx.x;
    const int w   = tid >> 6;              // wave index == patch pw within stripe
    const int l   = tid & 63;
    const int p   = ph * 8 + w;            // global patch id for this wave

    // stage mapping: thread t handles the contiguous float4 at stripe offset 4t
    const int r_t  = tid >> 5;
    const int pw_t = (tid >> 2) & 7;
    const int jj_t = (tid & 3) * 4;
    const int lds_stage = pw_t * PSTRIDE + r_t * 16 + jj_t;   // patch-major slot
    const int goff = tid * 4;                                  // contiguous offset

    // ---- weight preload (per wave, its patch) ----
    v4f we4[HID];
#pragma unroll
    for (int h = 0; h < HID; ++h)
        we4[h] = *(const v4f*)(We + ((size_t)(p * HID + h)) * DD + l * 4);
    float bev[HID];
#pragma unroll
    for (int h = 0; h < HID; ++h) bev[h] = be[p * HID + h];
    v4f wd4[4][2];
#pragma unroll
    for (int c = 0; c < 4; ++c) {
        const v4f* wp = (const v4f*)(Wd + ((size_t)(p * DD + l * 4 + c)) * HID);
        wd4[c][0] = wp[0];
        wd4[c][1] = wp[1];
    }
    v4f bdv = *(const v4f*)(bd + p * DD + l * 4);

    const bool b5 = (l & 32) != 0;
    const bool b4 = (l & 16) != 0;
    const bool b3 = (l & 8)  != 0;

    // stripe is CONTIGUOUS in memory: rows ph*16 .. ph*16+15
    const float* xs = x   + (size_t)(sg * G) * IMG + ph * 2048;
    float*       os = out + (size_t)(sg * G) * IMG + ph * 2048;

    // prologue: stage sample 0; hold sample 1 in regs
    {
        v4f x0 = *(const v4f*)(xs + goff);
        *(v4f*)&Xb[0][lds_stage] = x0;
    }
    v4f xn = *(const v4f*)(xs + IMG + goff);

#pragma unroll 1
    for (int s = 0; s < G; ++s) {
        __syncthreads();   // the ONLY barrier per sample

        // issue load for sample s+2 AFTER the barrier: it drains at the NEXT
        // barrier, with this whole compute+stage+store phase hiding its latency
        v4f xm;
        if (s + 2 < G)
            xm = *(const v4f*)(xs + (size_t)(s + 2) * IMG + goff);

        // ---- compute sample s: wave w owns patch p; lane l owns d = 4l..4l+3
        v4f xv = *(const v4f*)&Xb[s & 1][w * PSTRIDE + 4 * l];

        float z[HID];
#pragma unroll
        for (int h = 0; h < HID; ++h)
            z[h] = fmaf(we4[h].x, xv.x,
                   fmaf(we4[h].y, xv.y,
                   fmaf(we4[h].z, xv.z, we4[h].w * xv.w)));

        // reduce-scatter: mask32 keep 4, mask16 keep 2, mask8 keep 1
        float a[4];
#pragma unroll
        for (int c = 0; c < 4; ++c) {
            float send = b5 ? z[c]     : z[c + 4];
            float keep = b5 ? z[c + 4] : z[c];
            a[c] = keep + __shfl_xor(send, 32);
        }
        float bb[2];
#pragma unroll
        for (int c = 0; c < 2; ++c) {
            float send = b4 ? a[c]     : a[c + 2];
            float keep = b4 ? a[c + 2] : a[c];
            bb[c] = keep + __shfl_xor(send, 16);
        }
        float s1;
        {
            float send = b3 ? bb[0] : bb[1];
            float keep = b3 ? bb[1] : bb[0];
            s1 = keep + __shfl_xor(send, 8);
        }
#pragma unroll
        for (int m = 4; m >= 1; m >>= 1)
            s1 += __shfl_xor(s1, m);

        // broadcast (h lives at lane h*8) + decode + sigmoid
        float zf[HID];
#pragma unroll
        for (int h = 0; h < HID; ++h)
            zf[h] = rlane(s1, h * 8) + bev[h];

        v4f o;
#pragma unroll
        for (int c = 0; c < 4; ++c) {
            float acc = bdv[c];
#pragma unroll
            for (int h = 0; h < 4; ++h) acc = fmaf(wd4[c][0][h], zf[h], acc);
#pragma unroll
            for (int h = 0; h < 4; ++h) acc = fmaf(wd4[c][1][h], zf[h + 4], acc);
            o[c] = __builtin_amdgcn_rcpf(1.0f + __expf(-acc));
        }
        *(v4f*)&Ob[s & 1][w * PSTRIDE + 4 * l] = o;

        // stage next sample's input (reg-held since previous iteration)
        if (s + 1 < G)
            *(v4f*)&Xb[(s + 1) & 1][lds_stage] = xn;

        // store PREVIOUS sample's output (written before this iter's barrier)
        if (s > 0) {
            v4f ov = *(const v4f*)&Ob[(s - 1) & 1][lds_stage];
            __builtin_nontemporal_store(ov, (v4f*)(os + (size_t)(s - 1) * IMG + goff));
        }
        xn = xm;
    }

    // epilogue: store the last sample
    __syncthreads();
    {
        v4f ov = *(const v4f*)&Ob[(G - 1) & 1][lds_stage];
        __builtin_nontemporal_store(ov, (v4f*)(os + (size_t)(G - 1) * IMG + goff));
    }
}

extern "C" void kernel_launch(void* const* d_in, const int* in_sizes, int n_in,
                              void* d_out, int out_size, void* d_ws, size_t ws_size,
                              hipStream_t stream) {
    const float* x  = (const float*)d_in[0];
    const float* We = (const float*)d_in[1];
    const float* be = (const float*)d_in[2];
    const float* Wd = (const float*)d_in[3];
    const float* bd = (const float*)d_in[4];
    float* out = (float*)d_out;

    const int n_total = in_sizes[0] / IMG;          // 2048
    const int grid    = 16 * (n_total / G);         // 16 stripes * 128 groups = 2048
    lca_kernel<<<dim3(grid), dim3(512), 0, stream>>>(x, We, be, Wd, bd, out);
}

// Round 11
// 105.151 us; speedup vs baseline: 4.0083x; 1.0848x over previous
//
#include <hip/hip_runtime.h>

#define HH 256
#define WW 128
#define DD 256
#define HID 8
#define G 16              // samples per block
#define NP2 (G / 2)       // 8 sample-pairs
#define PSTRIDE 272       // padded per-patch stride (mod 32 == 16)
#define ZSTR 12           // per-patch stride in z buffer (48B: conflict-free v4f)
#define IMG (HH * WW)

typedef float v4f __attribute__((ext_vector_type(4)));

__global__ __launch_bounds__(512, 4)
void lca_kernel(const float* __restrict__ x, const float* __restrict__ We,
                const float* __restrict__ be, const float* __restrict__ Wd,
                const float* __restrict__ bd, float* __restrict__ out) {
    __shared__ float Xb[2][2][8 * PSTRIDE];  // [pair-buf][sample-in-pair][patch-major]
    __shared__ float Zb[2][2][8 * ZSTR];     // [pair-buf][sample][patch*12 + h]

    const int bid = blockIdx.x;
    const int ph  = bid & 15;               // stripe (16 rows)
    const int sg  = bid >> 4;               // sample group
    const int tid = threadIdx.x;
    const int w   = tid >> 6;               // wave = encode patch pw
    const int l   = tid & 63;
    const int p_w = ph * 8 + w;             // encode patch (wave-mapped)

    // stage mapping: thread handles contiguous float4 at stripe offset 4*tid
    const int r_t  = tid >> 5;
    const int pw_t = (tid >> 2) & 7;
    const int jj_t = (tid & 3) * 4;
    const int lds_stage = pw_t * PSTRIDE + r_t * 16 + jj_t;
    const int goff = tid * 4;
    const int p_t  = ph * 8 + pw_t;         // decode patch (stage-mapped)
    const int d_t  = r_t * 16 + jj_t;       // decode element base

    // ---- encode weights: wave-mapped (lane l owns d = 4l..4l+3 of patch p_w)
    v4f we4[HID];
#pragma unroll
    for (int h = 0; h < HID; ++h)
        we4[h] = *(const v4f*)(We + ((size_t)(p_w * HID + h)) * DD + l * 4);
    // encode bias: only the writer lane (l = 8h) needs h = l>>3
    const float bew = be[p_w * HID + (l >> 3)];

    // ---- decode weights: stage-mapped (thread decodes elements d_t..d_t+3 of p_t)
    v4f wd4[4][2];
#pragma unroll
    for (int c = 0; c < 4; ++c) {
        const v4f* wp = (const v4f*)(Wd + ((size_t)(p_t * DD + d_t + c)) * HID);
        wd4[c][0] = wp[0];
        wd4[c][1] = wp[1];
    }
    v4f bdv = *(const v4f*)(bd + p_t * DD + d_t);

    const bool b5 = (l & 32) != 0;
    const bool b4 = (l & 16) != 0;
    const bool b3 = (l & 8)  != 0;

    const float* xs = x   + (size_t)(sg * G) * IMG + ph * 2048;
    float*       os = out + (size_t)(sg * G) * IMG + ph * 2048;

    // prologue: stage pair 0
    {
        v4f a0 = *(const v4f*)(xs + goff);
        v4f a1 = *(const v4f*)(xs + IMG + goff);
        *(v4f*)&Xb[0][0][lds_stage] = a0;
        *(v4f*)&Xb[0][1][lds_stage] = a1;
    }

#pragma unroll 1
    for (int q = 0; q < NP2; ++q) {
        __syncthreads();   // Xb[q&1], Zb[(q-1)&1] visible

        // issue next pair's loads early; staged at the bottom of THIS iteration,
        // so the whole body covers their latency
        v4f xr0, xr1;
        if (q + 1 < NP2) {
            xr0 = *(const v4f*)(xs + (size_t)(2 * q + 2) * IMG + goff);
            xr1 = *(const v4f*)(xs + (size_t)(2 * q + 3) * IMG + goff);
        }

        // ---- decode pair q-1 (independent of this iteration's encode) ----
        if (q > 0) {
#pragma unroll
            for (int ss = 0; ss < 2; ++ss) {
                const float* zp = &Zb[(q - 1) & 1][ss][pw_t * ZSTR];
                v4f z0 = *(const v4f*)zp;
                v4f z1 = *(const v4f*)(zp + 4);
                v4f o;
#pragma unroll
                for (int c = 0; c < 4; ++c) {
                    float acc = bdv[c];
#pragma unroll
                    for (int h = 0; h < 4; ++h) acc = fmaf(wd4[c][0][h], z0[h], acc);
#pragma unroll
                    for (int h = 0; h < 4; ++h) acc = fmaf(wd4[c][1][h], z1[h], acc);
                    o[c] = __builtin_amdgcn_rcpf(1.0f + __expf(-acc));
                }
                __builtin_nontemporal_store(
                    o, (v4f*)(os + (size_t)(2 * (q - 1) + ss) * IMG + goff));
            }
        }

        // ---- encode pair q ----
#pragma unroll
        for (int ss = 0; ss < 2; ++ss) {
            v4f xv = *(const v4f*)&Xb[q & 1][ss][w * PSTRIDE + 4 * l];
            float z[HID];
#pragma unroll
            for (int h = 0; h < HID; ++h)
                z[h] = fmaf(we4[h].x, xv.x,
                       fmaf(we4[h].y, xv.y,
                       fmaf(we4[h].z, xv.z, we4[h].w * xv.w)));
            float a[4];
#pragma unroll
            for (int c = 0; c < 4; ++c) {
                float send = b5 ? z[c]     : z[c + 4];
                float keep = b5 ? z[c + 4] : z[c];
                a[c] = keep + __shfl_xor(send, 32);
            }
            float bb[2];
#pragma unroll
            for (int c = 0; c < 2; ++c) {
                float send = b4 ? a[c]     : a[c + 2];
                float keep = b4 ? a[c + 2] : a[c];
                bb[c] = keep + __shfl_xor(send, 16);
            }
            float s1;
            {
                float send = b3 ? bb[0] : bb[1];
                float keep = b3 ? bb[1] : bb[0];
                s1 = keep + __shfl_xor(send, 8);
            }
#pragma unroll
            for (int m = 4; m >= 1; m >>= 1)
                s1 += __shfl_xor(s1, m);
            // lane 8h holds the full sum for hidden h; one writer per group
            if ((l & 7) == 0)
                Zb[q & 1][ss][w * ZSTR + (l >> 3)] = s1 + bew;
        }

        // ---- stage pair q+1 (loads issued at top of this iteration) ----
        if (q + 1 < NP2) {
            *(v4f*)&Xb[(q + 1) & 1][0][lds_stage] = xr0;
            *(v4f*)&Xb[(q + 1) & 1][1][lds_stage] = xr1;
        }
    }

    // epilogue: decode the last pair
    __syncthreads();
#pragma unroll
    for (int ss = 0; ss < 2; ++ss) {
        const float* zp = &Zb[(NP2 - 1) & 1][ss][pw_t * ZSTR];
        v4f z0 = *(const v4f*)zp;
        v4f z1 = *(const v4f*)(zp + 4);
        v4f o;
#pragma unroll
        for (int c = 0; c < 4; ++c) {
            float acc = bdv[c];
#pragma unroll
            for (int h = 0; h < 4; ++h) acc = fmaf(wd4[c][0][h], z0[h], acc);
#pragma unroll
            for (int h = 0; h < 4; ++h) acc = fmaf(wd4[c][1][h], z1[h], acc);
            o[c] = __builtin_amdgcn_rcpf(1.0f + __expf(-acc));
        }
        __builtin_nontemporal_store(
            o, (v4f*)(os + (size_t)(2 * (NP2 - 1) + ss) * IMG + goff));
    }
}

extern "C" void kernel_launch(void* const* d_in, const int* in_sizes, int n_in,
                              void* d_out, int out_size, void* d_ws, size_t ws_size,
                              hipStream_t stream) {
    const float* x  = (const float*)d_in[0];
    const float* We = (const float*)d_in[1];
    const float* be = (const float*)d_in[2];
    const float* Wd = (const float*)d_in[3];
    const float* bd = (const float*)d_in[4];
    float* out = (float*)d_out;

    const int n_total = in_sizes[0] / IMG;          // 2048
    const int grid    = 16 * (n_total / G);         // 2048 blocks
    lca_kernel<<<dim3(grid), dim3(512), 0, stream>>>(x, We, be, Wd, bd, out);
}

// Round 13
// 95.652 us; speedup vs baseline: 4.4064x; 1.0993x over previous
//
#include <hip/hip_runtime.h>

#define HH 256
#define WW 128
#define DD 256
#define HID 8
#define G 16              // samples per block
#define NP2 (G / 2)       // 8 sample-pairs
#define PSTRIDE 272       // padded per-patch stride (mod 32 == 16)
#define ZSTR 16           // per-patch stride in z buffer (64B aligned reads)
#define IMG (HH * WW)

typedef float v4f __attribute__((ext_vector_type(4)));

// VALU cross-lane primitives (gfx950): no DS-pipe involvement
__device__ __forceinline__ void pl32swap(float& a, float& b) {
    asm("v_permlane32_swap_b32 %0, %1" : "+v"(a), "+v"(b));
}
__device__ __forceinline__ void pl16swap(float& a, float& b) {
    asm("v_permlane16_swap_b32 %0, %1" : "+v"(a), "+v"(b));
}
template <int CTRL>
__device__ __forceinline__ float dpp_get(float v) {
    return __int_as_float(__builtin_amdgcn_update_dpp(
        0, __float_as_int(v), CTRL, 0xf, 0xf, true));
}
#define DPP_QUAD_XOR1 177     // quad_perm [1,0,3,2]
#define DPP_QUAD_XOR2 78      // quad_perm [2,3,0,1]
#define DPP_ROW_ROR8  0x128   // row_ror:8 == xor8 within row of 16
#define DPP_HALF_MIRR 0x141   // row_half_mirror: i -> i^7 within each 8

__global__ __launch_bounds__(512, 4)
void lca_kernel(const float* __restrict__ x, const float* __restrict__ We,
                const float* __restrict__ be, const float* __restrict__ Wd,
                const float* __restrict__ bd, float* __restrict__ out) {
    __shared__ float Xb[2][2][8 * PSTRIDE];  // [pair-buf][sample][patch-major]
    __shared__ float Zb[2][2][8 * ZSTR];     // [pair-buf][sample][patch*16 + h]

    const int bid = blockIdx.x;
    const int ph  = bid & 15;               // stripe (16 rows)
    const int sg  = bid >> 4;               // sample group
    const int tid = threadIdx.x;
    const int w   = tid >> 6;               // wave = encode patch pw
    const int l   = tid & 63;
    const int p_w = ph * 8 + w;             // encode patch (wave-mapped)

    // stage mapping: thread handles contiguous float4 at stripe offset 4*tid
    const int r_t  = tid >> 5;
    const int pw_t = (tid >> 2) & 7;
    const int jj_t = (tid & 3) * 4;
    const int lds_stage = pw_t * PSTRIDE + r_t * 16 + jj_t;
    const int goff = tid * 4;
    const int p_t  = ph * 8 + pw_t;         // decode patch (stage-mapped)
    const int d_t  = r_t * 16 + jj_t;       // decode element base

    // ---- encode weights: wave-mapped (lane l owns d = 4l..4l+3 of patch p_w)
    v4f we4[HID];
#pragma unroll
    for (int h = 0; h < HID; ++h)
        we4[h] = *(const v4f*)(We + ((size_t)(p_w * HID + h)) * DD + l * 4);
    // encode bias: only the writer lane (l = 8h) needs h = l>>3
    const float bew = be[p_w * HID + (l >> 3)];

    // ---- decode weights: stage-mapped (thread decodes elements d_t..d_t+3 of p_t)
    v4f wd4[4][2];
#pragma unroll
    for (int c = 0; c < 4; ++c) {
        const v4f* wp = (const v4f*)(Wd + ((size_t)(p_t * DD + d_t + c)) * HID);
        wd4[c][0] = wp[0];
        wd4[c][1] = wp[1];
    }
    v4f bdv = *(const v4f*)(bd + p_t * DD + d_t);

    const bool b3 = (l & 8) != 0;

    const float* xs = x   + (size_t)(sg * G) * IMG + ph * 2048;
    float*       os = out + (size_t)(sg * G) * IMG + ph * 2048;

    // prologue: stage pair 0
    {
        v4f a0 = *(const v4f*)(xs + goff);
        v4f a1 = *(const v4f*)(xs + IMG + goff);
        *(v4f*)&Xb[0][0][lds_stage] = a0;
        *(v4f*)&Xb[0][1][lds_stage] = a1;
    }

#pragma unroll 1
    for (int q = 0; q < NP2; ++q) {
        __syncthreads();   // Xb[q&1], Zb[(q-1)&1] visible

        // issue next pair's loads; staged at the bottom of THIS iteration
        v4f xr0, xr1;
        if (q + 1 < NP2) {
            xr0 = *(const v4f*)(xs + (size_t)(2 * q + 2) * IMG + goff);
            xr1 = *(const v4f*)(xs + (size_t)(2 * q + 3) * IMG + goff);
        }

        // ---- decode pair q-1 (independent of this iteration's encode) ----
        if (q > 0) {
#pragma unroll
            for (int ss = 0; ss < 2; ++ss) {
                const float* zp = &Zb[(q - 1) & 1][ss][pw_t * ZSTR];
                v4f z0 = *(const v4f*)zp;
                v4f z1 = *(const v4f*)(zp + 4);
                v4f o;
#pragma unroll
                for (int c = 0; c < 4; ++c) {
                    float acc = bdv[c];
#pragma unroll
                    for (int h = 0; h < 4; ++h) acc = fmaf(wd4[c][0][h], z0[h], acc);
#pragma unroll
                    for (int h = 0; h < 4; ++h) acc = fmaf(wd4[c][1][h], z1[h], acc);
                    o[c] = __builtin_amdgcn_rcpf(1.0f + __expf(-acc));
                }
                __builtin_nontemporal_store(
                    o, (v4f*)(os + (size_t)(2 * (q - 1) + ss) * IMG + goff));
            }
        }

        // ---- encode pair q (reduction entirely on VALU cross-lane) ----
#pragma unroll
        for (int ss = 0; ss < 2; ++ss) {
            v4f xv = *(const v4f*)&Xb[q & 1][ss][w * PSTRIDE + 4 * l];
            float z[HID];
#pragma unroll
            for (int h = 0; h < HID; ++h)
                z[h] = fmaf(we4[h].x, xv.x,
                       fmaf(we4[h].y, xv.y,
                       fmaf(we4[h].z, xv.z, we4[h].w * xv.w)));

            // xor32: permlane32_swap; after sum, lane<32 holds h=c, lane>=32 h=c+4
            pl32swap(z[0], z[4]); float a0 = z[0] + z[4];
            pl32swap(z[1], z[5]); float a1 = z[1] + z[5];
            pl32swap(z[2], z[6]); float a2 = z[2] + z[6];
            pl32swap(z[3], z[7]); float a3 = z[3] + z[7];
            // xor16: permlane16_swap; h += 2*b4
            pl16swap(a0, a2); float c0 = a0 + a2;
            pl16swap(a1, a3); float c1 = a1 + a3;
            // xor8 with scatter by b3 (DPP row_ror:8); h = 4b5 + 2b4 + b3
            float keep = b3 ? c1 : c0;
            float send = b3 ? c0 : c1;
            float s1 = keep + dpp_get<DPP_ROW_ROR8>(send);
            // bits 0-2: quad xor1, xor2, then half-row mirror (i^7 completes octet)
            s1 += dpp_get<DPP_QUAD_XOR1>(s1);
            s1 += dpp_get<DPP_QUAD_XOR2>(s1);
            s1 += dpp_get<DPP_HALF_MIRR>(s1);

            // lane 8h holds the full sum for hidden h; one writer per octet
            if ((l & 7) == 0)
                Zb[q & 1][ss][w * ZSTR + (l >> 3)] = s1 + bew;
        }

        // ---- stage pair q+1 (loads issued at top of this iteration) ----
        if (q + 1 < NP2) {
            *(v4f*)&Xb[(q + 1) & 1][0][lds_stage] = xr0;
            *(v4f*)&Xb[(q + 1) & 1][1][lds_stage] = xr1;
        }
    }

    // epilogue: decode the last pair
    __syncthreads();
#pragma unroll
    for (int ss = 0; ss < 2; ++ss) {
        const float* zp = &Zb[(NP2 - 1) & 1][ss][pw_t * ZSTR];
        v4f z0 = *(const v4f*)zp;
        v4f z1 = *(const v4f*)(zp + 4);
        v4f o;
#pragma unroll
        for (int c = 0; c < 4; ++c) {
            float acc = bdv[c];
#pragma unroll
            for (int h = 0; h < 4; ++h) acc = fmaf(wd4[c][0][h], z0[h], acc);
#pragma unroll
            for (int h = 0; h < 4; ++h) acc = fmaf(wd4[c][1][h], z1[h], acc);
            o[c] = __builtin_amdgcn_rcpf(1.0f + __expf(-acc));
        }
        __builtin_nontemporal_store(
            o, (v4f*)(os + (size_t)(2 * (NP2 - 1) + ss) * IMG + goff));
    }
}

extern "C" void kernel_launch(void* const* d_in, const int* in_sizes, int n_in,
                              void* d_out, int out_size, void* d_ws, size_t ws_size,
                              hipStream_t stream) {
    const float* x  = (const float*)d_in[0];
    const float* We = (const float*)d_in[1];
    const float* be = (const float*)d_in[2];
    const float* Wd = (const float*)d_in[3];
    const float* bd = (const float*)d_in[4];
    float* out = (float*)d_out;

    const int n_total = in_sizes[0] / IMG;          // 2048
    const int grid    = 16 * (n_total / G);         // 2048 blocks
    lca_kernel<<<dim3(grid), dim3(512), 0, stream>>>(x, We, be, Wd, bd, out);
}